// Round 12
// baseline (135.731 us; speedup 1.0000x reference)
//
#include <hip/hip_runtime.h>
#include <stdint.h>

#define EPSN 1e-12f

typedef float f32x16 __attribute__((ext_vector_type(16)));
typedef float f32x4 __attribute__((ext_vector_type(4)));
typedef __bf16 bf16x8 __attribute__((ext_vector_type(8)));
typedef unsigned short u16x4 __attribute__((ext_vector_type(4)));

// ---- bf16 helpers ----
__device__ __forceinline__ unsigned short f2bf(float f) {
  union { float f; unsigned int u; } v; v.f = f;
  unsigned int u = v.u + 0x7FFFu + ((v.u >> 16) & 1u);
  return (unsigned short)(u >> 16);
}
__device__ __forceinline__ float bf2f(unsigned short h) {
  union { float f; unsigned int u; } v; v.u = ((unsigned int)h) << 16;
  return v.f;
}

// ---- workspace layout (ushort offsets) ----
// Fragment-major packed bf16 weights for 32x32x16 MFMA, K 258(+bias)->272:
//   addr = ((tile*NKS + ks)*64 + hi*32 + col)*8 + j
//   value = W[o = tile*32 + col][k = ks*16 + hi*8 + j]  (k=258 bias, >258 zero)
#define NKS 17
#define WQF_OFF 0
#define WKF_OFF (32 * NKS * 64 * 8)
#define WVP_OFF (2 * 32 * NKS * 64 * 8)

// =====================================================================
// prep: blocks [0,512) pack wq/wk (4 o-rows each); [512,1536) WVt.
// (verified-passing R9 version)
// =====================================================================
__global__ __launch_bounds__(256) void prep_kernel(
    const float* __restrict__ wq, const float* __restrict__ bq,
    const float* __restrict__ wk, const float* __restrict__ bk,
    const float* __restrict__ v, const float* __restrict__ wout,
    unsigned short* __restrict__ wsp) {
  int bid = blockIdx.x;
  if (bid < 512) {
    int isK = bid >= 256;
    int ob = (bid & 255) * 4;
    const float* w = isK ? wk : wq;
    const float* bb = isK ? bk : bq;
    unsigned short* dst = wsp + (isK ? WKF_OFF : WQF_OFF);
    for (int i = threadIdx.x; i < 4 * 129; i += 256) {
      int r = i / 129, q = i - r * 129;
      int o = ob + r, k = q * 2;
      float2 w2 = *(const float2*)(w + o * 258 + k);
      int g = o >> 5, col = o & 31;
      int ks = k >> 4, hi = (k >> 3) & 1, j = k & 7;
      uint32_t pk = (uint32_t)f2bf(w2.x) | ((uint32_t)f2bf(w2.y) << 16);
      *(uint32_t*)(dst + (((g * NKS + ks) * 64 + hi * 32 + col) << 3) + j) = pk;
    }
    for (int i = threadIdx.x; i < 4 * 14; i += 256) {
      int r = i / 14, kk = 258 + (i - r * 14);
      int o = ob + r;
      int g = o >> 5, col = o & 31;
      int ks = kk >> 4, hi = (kk >> 3) & 1, j = kk & 7;
      dst[(((g * NKS + ks) * 64 + hi * 32 + col) << 3) + j] =
          (kk == 258) ? f2bf(bb[o]) : (unsigned short)0;
    }
  } else {
    int idx = (bid - 512) * 256 + threadIdx.x;
    int fc = idx & 15, m = (idx >> 4) & 63, o = idx >> 10;
    const f32x4* wo = (const f32x4*)(wout + o * 256 + fc * 16);
    const f32x4* vm = (const f32x4*)(v + m * 256 + fc * 16);
    float s = 0.f;
#pragma unroll
    for (int f = 0; f < 4; ++f) {
      f32x4 a = wo[f], bvv = vm[f];
      s += a[0]*bvv[0] + a[1]*bvv[1] + a[2]*bvv[2] + a[3]*bvv[3];
    }
    s += __shfl_xor(s, 1, 64);
    s += __shfl_xor(s, 2, 64);
    s += __shfl_xor(s, 4, 64);
    s += __shfl_xor(s, 8, 64);
    if (fc == 0) wsp[WVP_OFF + o * 64 + m] = f2bf(s);
  }
}

// =====================================================================
// fused v12: MERGED Q+K sweep. 32 px/block, 512 blocks (2 generations/
// CU -> cross-generation HBM/compute overlap), 16 waves, 1 block/CU.
// Per wave-step: 4 A-loads (wq x2, wk x2) + ONE B ds_read serving 8
// MFMAs; 17 steps total (was 34). acc = 4 x f32x16 = 64 AGPR.
// K-norm s2 computed pre-barrier; only the qbar.k dot waits.
// =====================================================================
#define PXB 32   // pixels per block
#define KP 296   // xp row stride in shorts
#define QS 34    // qbar row stride (floats)
#define AT 76    // attnM row stride (shorts)

__global__ __launch_bounds__(1024, 4) void fused_kernel(
    const float* __restrict__ x, const float* __restrict__ pos,
    const unsigned short* __restrict__ wsp, const float* __restrict__ bout,
    float* __restrict__ out) {
  __shared__ __align__(16) unsigned short xp[PXB * KP];        // 18944 B
  __shared__ __align__(16) float qbarL[16 * QS];               // 2176 B
  __shared__ __align__(16) unsigned short attnM[PXB * AT];     // 4864 B
  __shared__ float boutL[256];                                 // 1024 B

  const int tid = threadIdx.x;
  const int lane = tid & 63;
  const int wid = __builtin_amdgcn_readfirstlane(tid >> 6);
  const int px = lane & 31, q2 = lane >> 5;
  const int P0 = blockIdx.x * PXB;
  const int b = P0 >> 12, s0 = P0 & 4095;

  // Per-wave A-stream bases (tiles 2wid, 2wid+1; +lane frag)
  const int wtoff = (2 * wid) * NKS * 512 + lane * 8;
  const unsigned short* wqf = wsp + WQF_OFF + wtoff;
  const unsigned short* wkf = wsp + WKF_OFF + wtoff;

  // ---- stage xp[p][c]: one f32x4-pair per thread (coalesced) ----
  uint32_t* xp32 = (uint32_t*)xp;
  {
    const float* xrow = x + b * 256 * 4096 + s0;
    int g = tid & 7, dcol = tid >> 3;             // dcol 0..127
    f32x4 lo = __builtin_nontemporal_load(
        (const f32x4*)(xrow + (2 * dcol) * 4096 + 4 * g));
    f32x4 hi = __builtin_nontemporal_load(
        (const f32x4*)(xrow + (2 * dcol + 1) * 4096 + 4 * g));
#pragma unroll
    for (int j = 0; j < 4; ++j) {
      int pp = 4 * g + j;
      xp32[pp * 148 + dcol] =
          (uint32_t)f2bf(lo[j]) | ((uint32_t)f2bf(hi[j]) << 16);
    }
    // tail cols: dcol 128 = (pos_y,pos_x), 129 = (1,0) bias, 130..147 = 0
    if (tid < 32 * 20) {
      int pp = tid & 31, dcol = 128 + (tid >> 5);
      float t0 = 0.f, t1 = 0.f;
      if (dcol == 128) { t0 = pos[s0 + pp]; t1 = pos[4096 + s0 + pp]; }
      else if (dcol == 129) { t0 = 1.0f; }
      xp32[pp * 148 + dcol] = (uint32_t)f2bf(t0) | ((uint32_t)f2bf(t1) << 16);
    }
  }
  if (tid < 256) boutL[tid] = bout[tid];
  for (int i = tid; i < 16 * QS; i += 1024) qbarL[i] = 0.f;
  __syncthreads();

  // ================= merged Q+K K-loop =================
  f32x16 aq0 = (f32x16)0.f, aq1 = (f32x16)0.f,
         ak0 = (f32x16)0.f, ak1 = (f32x16)0.f;
  {
    const unsigned short* bp = &xp[px * KP + q2 * 8];
    bf16x8 q0c = *(const bf16x8*)(wqf);
    bf16x8 q1c = *(const bf16x8*)(wqf + NKS * 512);
    bf16x8 k0c = *(const bf16x8*)(wkf);
    bf16x8 k1c = *(const bf16x8*)(wkf + NKS * 512);
#pragma unroll 1
    for (int i = 0; i < NKS - 1; ++i) {
      bf16x8 q0n = *(const bf16x8*)(wqf + (i + 1) * 512);
      bf16x8 q1n = *(const bf16x8*)(wqf + NKS * 512 + (i + 1) * 512);
      bf16x8 k0n = *(const bf16x8*)(wkf + (i + 1) * 512);
      bf16x8 k1n = *(const bf16x8*)(wkf + NKS * 512 + (i + 1) * 512);
      bf16x8 b0 = *(const bf16x8*)(bp + i * 16);
      aq0 = __builtin_amdgcn_mfma_f32_32x32x16_bf16(q0c, b0, aq0, 0, 0, 0);
      aq1 = __builtin_amdgcn_mfma_f32_32x32x16_bf16(q1c, b0, aq1, 0, 0, 0);
      ak0 = __builtin_amdgcn_mfma_f32_32x32x16_bf16(k0c, b0, ak0, 0, 0, 0);
      ak1 = __builtin_amdgcn_mfma_f32_32x32x16_bf16(k1c, b0, ak1, 0, 0, 0);
      q0c = q0n; q1c = q1n; k0c = k0n; k1c = k1n;
    }
    {
      bf16x8 b0 = *(const bf16x8*)(bp + (NKS - 1) * 16);
      aq0 = __builtin_amdgcn_mfma_f32_32x32x16_bf16(q0c, b0, aq0, 0, 0, 0);
      aq1 = __builtin_amdgcn_mfma_f32_32x32x16_bf16(q1c, b0, aq1, 0, 0, 0);
      ak0 = __builtin_amdgcn_mfma_f32_32x32x16_bf16(k0c, b0, ak0, 0, 0, 0);
      ak1 = __builtin_amdgcn_mfma_f32_32x32x16_bf16(k1c, b0, ak1, 0, 0, 0);
    }
  }

  // ---- q-norm per m; accumulate qbar partials ----
  {
    float qsum[8];
#pragma unroll
    for (int r = 0; r < 8; ++r) qsum[r] = 0.f;
#pragma unroll
    for (int ot = 0; ot < 2; ++ot) {
      const f32x16 a = ot ? aq1 : aq0;
      float s20 = 0.f, s21 = 0.f;
#pragma unroll
      for (int r = 0; r < 8; ++r) {
        s20 = fmaf(a[r], a[r], s20);
        s21 = fmaf(a[r + 8], a[r + 8], s21);
      }
      s20 += __shfl_xor(s20, 32, 64);
      s21 += __shfl_xor(s21, 32, 64);
      float i0 = 1.0f / fmaxf(sqrtf(s20), EPSN);
      float i1 = 1.0f / fmaxf(sqrtf(s21), EPSN);
#pragma unroll
      for (int r = 0; r < 8; ++r) qsum[r] += a[r] * i0 + a[r + 8] * i1;
    }
#pragma unroll
    for (int r = 0; r < 8; ++r) {
      int j = (r & 3) + ((r >> 2) << 3) + (q2 << 2);
      atomicAdd(&qbarL[j * QS + px], qsum[r] * (1.0f / 64.0f));
    }
  }

  // ---- k-norm sums (no qbar dependency): compute BEFORE the barrier ----
  float ki0[2], ki1[2];
#pragma unroll
  for (int ot = 0; ot < 2; ++ot) {
    const f32x16 a = ot ? ak1 : ak0;
    float s20 = 0.f, s21 = 0.f;
#pragma unroll
    for (int r = 0; r < 8; ++r) {
      s20 = fmaf(a[r], a[r], s20);
      s21 = fmaf(a[r + 8], a[r + 8], s21);
    }
    s20 += __shfl_xor(s20, 32, 64);
    s21 += __shfl_xor(s21, 32, 64);
    ki0[ot] = 1.0f / fmaxf(sqrtf(s20), EPSN);
    ki1[ot] = 1.0f / fmaxf(sqrtf(s21), EPSN);
  }
  __syncthreads();   // qbar atomics complete grid^W block-wide

  // ---- attn = (qbar . kn) ----
  {
    float qb[8];
#pragma unroll
    for (int r = 0; r < 8; ++r) {
      int j = (r & 3) + ((r >> 2) << 3) + (q2 << 2);
      qb[r] = qbarL[j * QS + px];
    }
#pragma unroll
    for (int ot = 0; ot < 2; ++ot) {
      const f32x16 a = ot ? ak1 : ak0;
      float sp0 = 0.f, sp1 = 0.f;
#pragma unroll
      for (int r = 0; r < 8; ++r) {
        sp0 = fmaf(qb[r], a[r], sp0);
        sp1 = fmaf(qb[r], a[r + 8], sp1);
      }
      sp0 += __shfl_xor(sp0, 32, 64);
      sp1 += __shfl_xor(sp1, 32, 64);
      if (q2 == 0) {
        int m0 = wid * 4 + ot * 2;
        attnM[px * AT + m0]     = f2bf(sp0 * ki0[ot]);
        attnM[px * AT + m0 + 1] = f2bf(sp1 * ki1[ot]);
      }
    }
  }
  __syncthreads();

  // ==== epilogue: out = x + bout + WVt @ attn (x from xp bf16; nt) ====
  if (wid < 8) {
    const int otile = wid;
    f32x16 e = (f32x16)0.f;
    const unsigned short* wv = wsp + WVP_OFF + (otile * 32 + px) * 64 + q2 * 8;
    const unsigned short* ab = &attnM[px * AT + q2 * 8];
#pragma unroll
    for (int ks = 0; ks < 4; ++ks) {
      bf16x8 av = *(const bf16x8*)(wv + ks * 16);
      bf16x8 bv = *(const bf16x8*)(ab + ks * 16);
      e = __builtin_amdgcn_mfma_f32_32x32x16_bf16(av, bv, e, 0, 0, 0);
    }
    const unsigned short* xl = &xp[px * KP + otile * 32 + (q2 << 2)];
#pragma unroll
    for (int rq = 0; rq < 4; ++rq) {
      u16x4 xq = *(const u16x4*)(xl + 8 * rq);
#pragma unroll
      for (int j = 0; j < 4; ++j) {
        const int r = rq * 4 + j;
        const int o = otile * 32 + j + (rq << 3) + (q2 << 2);
        const int gi = (b * 256 + o) * 4096 + s0 + px;
        __builtin_nontemporal_store(bf2f(xq[j]) + boutL[o] + e[r], &out[gi]);
      }
    }
  }
}

// =====================================================================
extern "C" void kernel_launch(void* const* d_in, const int* in_sizes, int n_in,
                              void* d_out, int out_size, void* d_ws, size_t ws_size,
                              hipStream_t stream) {
  const float* x    = (const float*)d_in[0];
  const float* pos  = (const float*)d_in[1];
  const float* wq   = (const float*)d_in[2];
  const float* bq   = (const float*)d_in[3];
  const float* wk   = (const float*)d_in[4];
  const float* bk   = (const float*)d_in[5];
  const float* v    = (const float*)d_in[6];
  const float* wout = (const float*)d_in[7];
  const float* bout = (const float*)d_in[8];
  float* out = (float*)d_out;
  unsigned short* wsp = (unsigned short*)d_ws;

  hipLaunchKernelGGL(prep_kernel, dim3(1536), dim3(256), 0, stream,
                     wq, bq, wk, bk, v, wout, wsp);
  hipLaunchKernelGGL(fused_kernel, dim3(512), dim3(1024), 0, stream,
                     x, pos, wsp, bout, out);
}